// Round 14
// baseline (41.701 us; speedup 1.0000x reference)
//
#include <hip/hip_runtime.h>

// VanillaGNN via MFMA: B=262144 graphs, N=8 nodes, DIN=3, DH=32, DOUT=1.
// Round-13 base (41.6us) + ONE exact change: a SINGLE shared f32x16
// accumulator for all three MFMA stages (L1 / GEMM1 / AGG). The three accs
// are sequentially dead; sharing should cut AGPR footprint 48->16 so
// VGPR+AGPR <= 128 -> 4 waves/SIMD bin (r13 stuck at 2: 80 VGPR + ~64 AGPR
// landed in the 256-reg bin; m69 occupancy steps at 64/128/256).
// Chain per wave (4 graphs = 32 node-rows):
//   y = A@x (24 fma) -> L1: P = W1split @ ysplit + b1 (2 kappa-packed MFMA,
//   relu) -> GEMM1: t = h1@W2 (split-bf16, 6 MFMA; pi both sides) ->
//   AGG: h2T = tT @ A32T (4 MFMA, thi only) -> in-register Wout reduction.
// Verified layouts (gfx950 mfma_f32_32x32x16_bf16, rounds 3-13):
//   A: lane row=l&31, k=s*16+8*(l>>5)+j   B: col=l&31, same k
//   C/D: col=l&31, row=(reg&3)+8*(reg>>2)+4*(l>>5)
// pi(kk) = rr(kk) = (kk&3)+8*(kk>>2)+4q  (logical index of reg kk).
// FETCH_SIZE ~12.3MB is the spill canary; absmax must stay EXACTLY 1.2207e-4.

typedef __bf16 bf16x8 __attribute__((ext_vector_type(8)));
typedef float  f32x16 __attribute__((ext_vector_type(16)));

#define GPT 16  // graphs per block tile (4 waves x 4 graphs)

__global__ __launch_bounds__(256, 2) void gnn_kernel(
    const float* __restrict__ x,       // [B,8,3]
    const int* __restrict__ ei,        // [2,32] int32
    const float* __restrict__ W1,      // [3,32]
    const float* __restrict__ b1,      // [32]
    const float* __restrict__ W2,      // [32,32]
    const float* __restrict__ b2,      // [32]
    const float* __restrict__ Wout,    // [32]
    const float* __restrict__ bout,    // [1]
    float* __restrict__ out,           // [B]
    int B, int ntiles)
{
    __shared__ float As[64];           // A[n][m] (n=dst)
    __shared__ float degs[8], dinvs[8];
    __shared__ float W1s[96], b1s[32], W2s[1024], b2s[32], Wouts[32];
    __shared__ float xs[2][GPT * 24];  // double-buffered [g][8][3]

    const int tid = threadIdx.x;

    // ---- stage weights / build A (once per block) ----
    if (tid < 96) W1s[tid] = W1[tid];
    if (tid < 64) As[tid] = 0.0f;
    if (tid < 32) { b1s[tid] = b1[tid]; b2s[tid] = b2[tid]; Wouts[tid] = Wout[tid]; }
    if (tid < 8)  degs[tid] = 1.0f;
    for (int i = tid; i < 1024; i += 256) W2s[i] = W2[i];
    __syncthreads();
    if (tid < 32) { int d = ei[32 + tid]; atomicAdd(&degs[d], 1.0f); }
    __syncthreads();
    if (tid < 8) dinvs[tid] = 1.0f / sqrtf(degs[tid]);
    __syncthreads();
    if (tid < 32) {
        int s = ei[tid], d = ei[32 + tid];
        atomicAdd(&As[d * 8 + s], dinvs[s] * dinvs[d]);
    } else if (tid < 40) {
        int n = tid - 32;
        atomicAdd(&As[n * 8 + n], dinvs[n] * dinvs[n]);
    }
    __syncthreads();

    // ---- per-lane constants ----
    const int lane = tid & 63;
    const int wv   = tid >> 6;    // wave 0..3
    const int r    = lane & 31;
    const int q    = lane >> 5;   // k-half / row-half selector
    const int n8   = r & 7;       // node within graph
    const int gl   = r >> 3;      // graph within wave
    const int g    = wv * 4 + gl; // block-local graph

    float arow[8];
    #pragma unroll
    for (int m = 0; m < 8; m++) arow[m] = As[n8 * 8 + m];

    // W1^T A-frags, kappa-packed: slots 0-2 = W1[j][r] (hi step0 / lo step1),
    // slot 3 = b1[r] (hi step0 / lo step1; paired with B slot3 = q?0:1)
    bf16x8 w1Ahi, w1Alo;
    #pragma unroll
    for (int j = 0; j < 8; j++) { w1Ahi[j] = (__bf16)0.0f; w1Alo[j] = (__bf16)0.0f; }
    #pragma unroll
    for (int j = 0; j < 3; j++) {
        float v = W1s[j * 32 + r];
        __bf16 h = (__bf16)v;
        w1Ahi[j] = h; w1Alo[j] = (__bf16)(v - (float)h);
    }
    {
        float v = b1s[r];
        __bf16 h = (__bf16)v;
        w1Ahi[3] = h; w1Alo[3] = (__bf16)(v - (float)h);
    }

    // W2 B-frags in pi-order (split): slot (s,j), kk=8s+j ->
    //   hidden-in rr(kk) = (kk&3)+8*(kk>>2)+4q ; value W2[rr(kk)][r]
    bf16x8 w2hi[2], w2lo[2];
    #pragma unroll
    for (int s = 0; s < 2; s++) {
        #pragma unroll
        for (int j = 0; j < 8; j++) {
            int kk = 8 * s + j;
            int hid = (kk & 3) + 8 * (kk >> 2) + 4 * q;
            float v = W2s[hid * 32 + r];
            __bf16 h = (__bf16)v;
            w2hi[s][j] = h;
            w2lo[s][j] = (__bf16)(v - (float)h);
        }
    }
    // A32T B-frags in pi-order: slot (s,j), kk=8s+j -> node (kk&3)+4q of graph kk>>2
    bf16x8 a32hi[2], a32lo[2];
    #pragma unroll
    for (int s = 0; s < 2; s++) {
        #pragma unroll
        for (int j = 0; j < 8; j++) {
            int kk = 8 * s + j;
            float v = ((kk >> 2) == gl) ? arow[(kk & 3) + 4 * q] : 0.0f;
            __bf16 h = (__bf16)v;
            a32hi[s][j] = h;
            a32lo[s][j] = (__bf16)(v - (float)h);
        }
    }
    // epilogue per-reg constants: reg k holds hidden row hk = rr(k)
    float b2r[16], woutr[16];
    #pragma unroll
    for (int k = 0; k < 16; k++) {
        int hk = (k & 3) + 8 * (k >> 2) + 4 * q;
        b2r[k] = b2s[hk]; woutr[k] = Wouts[hk];
    }
    const float boutv = bout[0];

    // ---- x prefetch (tile 0) ----
    const float4* x4 = reinterpret_cast<const float4*>(x);
    float4 nxt;
    if (tid < 96 && blockIdx.x < ntiles)
        nxt = x4[(long long)blockIdx.x * 96 + tid];
    int buf = 0;

    // ---- tile loop: 1 barrier/tile; prefetch issued after the barrier ----
    for (int tile = blockIdx.x; tile < ntiles; tile += gridDim.x) {
        const long long gbase = (long long)tile * GPT;
        if (tid < 96) *reinterpret_cast<float4*>(&xs[buf][tid * 4]) = nxt;
        __syncthreads();
        int tnext = tile + gridDim.x;
        if (tid < 96 && tnext < ntiles)
            nxt = x4[(long long)tnext * 96 + tid];   // in flight during compute

        // ---- y = A@x for node-row r (24 fma) ----
        float xv[24];
        #pragma unroll
        for (int i = 0; i < 6; i++) {
            float4 v = *reinterpret_cast<float4*>(&xs[buf][g * 24 + i * 4]);
            xv[4 * i] = v.x; xv[4 * i + 1] = v.y; xv[4 * i + 2] = v.z; xv[4 * i + 3] = v.w;
        }
        float y0 = 0.f, y1 = 0.f, y2 = 0.f;
        #pragma unroll
        for (int m = 0; m < 8; m++) {
            y0 = fmaf(arow[m], xv[m * 3 + 0], y0);
            y1 = fmaf(arow[m], xv[m * 3 + 1], y1);
            y2 = fmaf(arow[m], xv[m * 3 + 2], y2);
        }

        // ---- ONE shared accumulator for all three MFMA stages ----
        f32x16 vacc;

        // ---- layer 1 via 2 kappa-packed MFMAs (bias in slot 3) ----
        bf16x8 yB;
        #pragma unroll
        for (int j = 0; j < 8; j++) yB[j] = (__bf16)0.0f;
        {
            __bf16 h0 = (__bf16)y0, h1b = (__bf16)y1, h2b = (__bf16)y2;
            __bf16 l0 = (__bf16)(y0 - (float)h0);
            __bf16 l1 = (__bf16)(y1 - (float)h1b);
            __bf16 l2 = (__bf16)(y2 - (float)h2b);
            yB[0] = q ? l0 : h0; yB[1] = q ? l1 : h1b; yB[2] = q ? l2 : h2b;
            yB[3] = q ? (__bf16)0.0f : (__bf16)1.0f;
        }
        #pragma unroll
        for (int k = 0; k < 16; k++) vacc[k] = 0.0f;
        vacc = __builtin_amdgcn_mfma_f32_32x32x16_bf16(w1Ahi, yB, vacc, 0, 0, 0);
        vacc = __builtin_amdgcn_mfma_f32_32x32x16_bf16(w1Alo, yB, vacc, 0, 0, 0);

        // ---- relu -> h1 (lane=node, regs=hidden rr); split to GEMM1 A-frags ----
        bf16x8 phi[2], plo[2];
        #pragma unroll
        for (int s = 0; s < 2; s++) {
            #pragma unroll
            for (int j = 0; j < 8; j++) {
                float v = fmaxf(vacc[8 * s + j], 0.0f);
                __bf16 h = (__bf16)v;
                phi[s][j] = h;
                plo[s][j] = (__bf16)(v - (float)h);
            }
        }

        // ---- GEMM1: t = h1 @ W2 (split-bf16, pi on k both sides) ----
        #pragma unroll
        for (int k = 0; k < 16; k++) vacc[k] = 0.0f;
        vacc = __builtin_amdgcn_mfma_f32_32x32x16_bf16(phi[0], w2hi[0], vacc, 0, 0, 0);
        vacc = __builtin_amdgcn_mfma_f32_32x32x16_bf16(phi[0], w2lo[0], vacc, 0, 0, 0);
        vacc = __builtin_amdgcn_mfma_f32_32x32x16_bf16(plo[0], w2hi[0], vacc, 0, 0, 0);
        vacc = __builtin_amdgcn_mfma_f32_32x32x16_bf16(phi[1], w2hi[1], vacc, 0, 0, 0);
        vacc = __builtin_amdgcn_mfma_f32_32x32x16_bf16(phi[1], w2lo[1], vacc, 0, 0, 0);
        vacc = __builtin_amdgcn_mfma_f32_32x32x16_bf16(plo[1], w2hi[1], vacc, 0, 0, 0);

        // ---- tT A-frag: hi-only DIRECT conversion (tlo dropped: r12-validated) ----
        bf16x8 thi[2];
        #pragma unroll
        for (int s = 0; s < 2; s++) {
            #pragma unroll
            for (int j = 0; j < 8; j++)
                thi[s][j] = (__bf16)vacc[8 * s + j];
        }

        // ---- aggregation: h2T = tT @ A32T (4 MFMA, + b2 folded into init) ----
        #pragma unroll
        for (int k = 0; k < 16; k++) vacc[k] = b2r[k];
        vacc = __builtin_amdgcn_mfma_f32_32x32x16_bf16(thi[0], a32hi[0], vacc, 0, 0, 0);
        vacc = __builtin_amdgcn_mfma_f32_32x32x16_bf16(thi[0], a32lo[0], vacc, 0, 0, 0);
        vacc = __builtin_amdgcn_mfma_f32_32x32x16_bf16(thi[1], a32hi[1], vacc, 0, 0, 0);
        vacc = __builtin_amdgcn_mfma_f32_32x32x16_bf16(thi[1], a32lo[1], vacc, 0, 0, 0);

        // ---- epilogue: lane=node, regs=hidden -> in-register reduction ----
        float ssum = 0.0f;
        #pragma unroll
        for (int k = 0; k < 16; k++)
            ssum = fmaf(fmaxf(vacc[k], 0.0f), woutr[k], ssum);
        ssum += __shfl_xor(ssum, 32, 64);          // other hidden half
        float o = fmaxf(ssum + boutv, 0.0f);       // relu per node
        o += __shfl_xor(o, 1, 64);
        o += __shfl_xor(o, 2, 64);
        o += __shfl_xor(o, 4, 64);                 // sum 8 nodes of my graph
        if (q == 0 && n8 == 0) {
            long long gg = gbase + g;
            if (gg < (long long)B) out[gg] = o * 0.125f;
        }
        buf ^= 1;
    }
}

extern "C" void kernel_launch(void* const* d_in, const int* in_sizes, int n_in,
                              void* d_out, int out_size, void* d_ws, size_t ws_size,
                              hipStream_t stream) {
    const float* x    = (const float*)d_in[0];
    const int*   ei   = (const int*)d_in[1];
    const float* W1   = (const float*)d_in[2];
    const float* b1   = (const float*)d_in[3];
    const float* W2   = (const float*)d_in[4];
    const float* b2   = (const float*)d_in[5];
    const float* Wout = (const float*)d_in[6];
    const float* bout = (const float*)d_in[7];
    float* out = (float*)d_out;
    (void)d_ws; (void)ws_size; (void)out_size; (void)n_in;

    const int B = in_sizes[0] / 24;                 // 262144
    const int ntiles = (B + GPT - 1) / GPT;         // 16384
    const int grid = ntiles < 2048 ? ntiles : 2048; // grid-stride, 8 iters/block
    gnn_kernel<<<grid, 256, 0, stream>>>(x, ei, W1, b1, W2, b2, Wout, bout, out, B, ntiles);
}

// Round 15
// 37.194 us; speedup vs baseline: 1.1212x; 1.1212x over previous
//
#include <hip/hip_runtime.h>

// VanillaGNN via MFMA: B=262144 graphs, N=8 nodes, DIN=3, DH=32, DOUT=1.
// Round-13/14 base (41.6us) + TWO precision drops to flip the 128-reg bin:
//  (1) drop a32lo (B-side lo of AGG; mirror of r12/r13's measured-free tlo
//      drop) -> AGG = 2 MFMA, -8 persistent regs
//  (2) drop w2lo (W2 lo in GEMM1; h1-side plo kept) -> GEMM1 = 4 MFMA,
//      -16 persistent regs
// Goal: live set ~112 <= 128 -> 4 waves/SIMD naturally (NEVER force via
// launch_bounds: r9/r12 spill lesson). Pre-commit: absmax > 4e-4 -> restore
// w2lo next round.
// Chain per wave (4 graphs = 32 node-rows):
//   y = A@x (24 fma) -> L1: P = W1split @ ysplit + b1 (2 kappa-packed MFMA,
//   relu) -> GEMM1: t = h1@bf16(W2) (4 MFMA; pi both sides) ->
//   AGG: h2T = bf16(tT) @ bf16(A32T) (2 MFMA) -> in-register Wout reduction.
// Verified layouts (gfx950 mfma_f32_32x32x16_bf16, rounds 3-14):
//   A: lane row=l&31, k=s*16+8*(l>>5)+j   B: col=l&31, same k
//   C/D: col=l&31, row=(reg&3)+8*(reg>>2)+4*(l>>5)
// pi(kk) = rr(kk) = (kk&3)+8*(kk>>2)+4q  (logical index of reg kk).
// FETCH_SIZE ~12.3MB is the spill canary.

typedef __bf16 bf16x8 __attribute__((ext_vector_type(8)));
typedef float  f32x16 __attribute__((ext_vector_type(16)));

#define GPT 16  // graphs per block tile (4 waves x 4 graphs)

__global__ __launch_bounds__(256, 2) void gnn_kernel(
    const float* __restrict__ x,       // [B,8,3]
    const int* __restrict__ ei,        // [2,32] int32
    const float* __restrict__ W1,      // [3,32]
    const float* __restrict__ b1,      // [32]
    const float* __restrict__ W2,      // [32,32]
    const float* __restrict__ b2,      // [32]
    const float* __restrict__ Wout,    // [32]
    const float* __restrict__ bout,    // [1]
    float* __restrict__ out,           // [B]
    int B, int ntiles)
{
    __shared__ float As[64];           // A[n][m] (n=dst)
    __shared__ float degs[8], dinvs[8];
    __shared__ float W1s[96], b1s[32], W2s[1024], b2s[32], Wouts[32];
    __shared__ float xs[2][GPT * 24];  // double-buffered [g][8][3]

    const int tid = threadIdx.x;

    // ---- stage weights / build A (once per block) ----
    if (tid < 96) W1s[tid] = W1[tid];
    if (tid < 64) As[tid] = 0.0f;
    if (tid < 32) { b1s[tid] = b1[tid]; b2s[tid] = b2[tid]; Wouts[tid] = Wout[tid]; }
    if (tid < 8)  degs[tid] = 1.0f;
    for (int i = tid; i < 1024; i += 256) W2s[i] = W2[i];
    __syncthreads();
    if (tid < 32) { int d = ei[32 + tid]; atomicAdd(&degs[d], 1.0f); }
    __syncthreads();
    if (tid < 8) dinvs[tid] = 1.0f / sqrtf(degs[tid]);
    __syncthreads();
    if (tid < 32) {
        int s = ei[tid], d = ei[32 + tid];
        atomicAdd(&As[d * 8 + s], dinvs[s] * dinvs[d]);
    } else if (tid < 40) {
        int n = tid - 32;
        atomicAdd(&As[n * 8 + n], dinvs[n] * dinvs[n]);
    }
    __syncthreads();

    // ---- per-lane constants ----
    const int lane = tid & 63;
    const int wv   = tid >> 6;    // wave 0..3
    const int r    = lane & 31;
    const int q    = lane >> 5;   // k-half / row-half selector
    const int n8   = r & 7;       // node within graph
    const int gl   = r >> 3;      // graph within wave
    const int g    = wv * 4 + gl; // block-local graph

    float arow[8];
    #pragma unroll
    for (int m = 0; m < 8; m++) arow[m] = As[n8 * 8 + m];

    // W1^T A-frags, kappa-packed: slots 0-2 = W1[j][r] (hi step0 / lo step1),
    // slot 3 = b1[r] (hi step0 / lo step1; paired with B slot3 = q?0:1)
    bf16x8 w1Ahi, w1Alo;
    #pragma unroll
    for (int j = 0; j < 8; j++) { w1Ahi[j] = (__bf16)0.0f; w1Alo[j] = (__bf16)0.0f; }
    #pragma unroll
    for (int j = 0; j < 3; j++) {
        float v = W1s[j * 32 + r];
        __bf16 h = (__bf16)v;
        w1Ahi[j] = h; w1Alo[j] = (__bf16)(v - (float)h);
    }
    {
        float v = b1s[r];
        __bf16 h = (__bf16)v;
        w1Ahi[3] = h; w1Alo[3] = (__bf16)(v - (float)h);
    }

    // W2 B-frags in pi-order (hi only; w2lo dropped): slot (s,j), kk=8s+j ->
    //   hidden-in rr(kk) = (kk&3)+8*(kk>>2)+4q ; value bf16(W2[rr(kk)][r])
    bf16x8 w2hi[2];
    #pragma unroll
    for (int s = 0; s < 2; s++) {
        #pragma unroll
        for (int j = 0; j < 8; j++) {
            int kk = 8 * s + j;
            int hid = (kk & 3) + 8 * (kk >> 2) + 4 * q;
            w2hi[s][j] = (__bf16)W2s[hid * 32 + r];
        }
    }
    // A32T B-frags in pi-order (hi only; a32lo dropped): slot (s,j), kk=8s+j
    //   -> node (kk&3)+4q of graph kk>>2, gated to own graph
    bf16x8 a32hi[2];
    #pragma unroll
    for (int s = 0; s < 2; s++) {
        #pragma unroll
        for (int j = 0; j < 8; j++) {
            int kk = 8 * s + j;
            float v = ((kk >> 2) == gl) ? arow[(kk & 3) + 4 * q] : 0.0f;
            a32hi[s][j] = (__bf16)v;
        }
    }
    // epilogue per-reg constants: reg k holds hidden row hk = rr(k)
    float b2r[16], woutr[16];
    #pragma unroll
    for (int k = 0; k < 16; k++) {
        int hk = (k & 3) + 8 * (k >> 2) + 4 * q;
        b2r[k] = b2s[hk]; woutr[k] = Wouts[hk];
    }
    const float boutv = bout[0];

    // ---- x prefetch (tile 0) ----
    const float4* x4 = reinterpret_cast<const float4*>(x);
    float4 nxt;
    if (tid < 96 && blockIdx.x < ntiles)
        nxt = x4[(long long)blockIdx.x * 96 + tid];
    int buf = 0;

    // ---- tile loop: 1 barrier/tile; prefetch issued after the barrier ----
    for (int tile = blockIdx.x; tile < ntiles; tile += gridDim.x) {
        const long long gbase = (long long)tile * GPT;
        if (tid < 96) *reinterpret_cast<float4*>(&xs[buf][tid * 4]) = nxt;
        __syncthreads();
        int tnext = tile + gridDim.x;
        if (tid < 96 && tnext < ntiles)
            nxt = x4[(long long)tnext * 96 + tid];   // in flight during compute

        // ---- y = A@x for node-row r (24 fma) ----
        float xv[24];
        #pragma unroll
        for (int i = 0; i < 6; i++) {
            float4 v = *reinterpret_cast<float4*>(&xs[buf][g * 24 + i * 4]);
            xv[4 * i] = v.x; xv[4 * i + 1] = v.y; xv[4 * i + 2] = v.z; xv[4 * i + 3] = v.w;
        }
        float y0 = 0.f, y1 = 0.f, y2 = 0.f;
        #pragma unroll
        for (int m = 0; m < 8; m++) {
            y0 = fmaf(arow[m], xv[m * 3 + 0], y0);
            y1 = fmaf(arow[m], xv[m * 3 + 1], y1);
            y2 = fmaf(arow[m], xv[m * 3 + 2], y2);
        }

        // ---- shared accumulator for all three MFMA stages ----
        f32x16 vacc;

        // ---- layer 1 via 2 kappa-packed MFMAs (bias in slot 3) ----
        bf16x8 yB;
        #pragma unroll
        for (int j = 0; j < 8; j++) yB[j] = (__bf16)0.0f;
        {
            __bf16 h0 = (__bf16)y0, h1b = (__bf16)y1, h2b = (__bf16)y2;
            __bf16 l0 = (__bf16)(y0 - (float)h0);
            __bf16 l1 = (__bf16)(y1 - (float)h1b);
            __bf16 l2 = (__bf16)(y2 - (float)h2b);
            yB[0] = q ? l0 : h0; yB[1] = q ? l1 : h1b; yB[2] = q ? l2 : h2b;
            yB[3] = q ? (__bf16)0.0f : (__bf16)1.0f;
        }
        #pragma unroll
        for (int k = 0; k < 16; k++) vacc[k] = 0.0f;
        vacc = __builtin_amdgcn_mfma_f32_32x32x16_bf16(w1Ahi, yB, vacc, 0, 0, 0);
        vacc = __builtin_amdgcn_mfma_f32_32x32x16_bf16(w1Alo, yB, vacc, 0, 0, 0);

        // ---- relu -> h1 (lane=node, regs=hidden rr); split to GEMM1 A-frags ----
        bf16x8 phi[2], plo[2];
        #pragma unroll
        for (int s = 0; s < 2; s++) {
            #pragma unroll
            for (int j = 0; j < 8; j++) {
                float v = fmaxf(vacc[8 * s + j], 0.0f);
                __bf16 h = (__bf16)v;
                phi[s][j] = h;
                plo[s][j] = (__bf16)(v - (float)h);
            }
        }

        // ---- GEMM1: t = h1 @ bf16(W2) (4 MFMA; h1-split kept, w2lo dropped) ----
        #pragma unroll
        for (int k = 0; k < 16; k++) vacc[k] = 0.0f;
        vacc = __builtin_amdgcn_mfma_f32_32x32x16_bf16(phi[0], w2hi[0], vacc, 0, 0, 0);
        vacc = __builtin_amdgcn_mfma_f32_32x32x16_bf16(plo[0], w2hi[0], vacc, 0, 0, 0);
        vacc = __builtin_amdgcn_mfma_f32_32x32x16_bf16(phi[1], w2hi[1], vacc, 0, 0, 0);
        vacc = __builtin_amdgcn_mfma_f32_32x32x16_bf16(plo[1], w2hi[1], vacc, 0, 0, 0);

        // ---- tT A-frag: hi-only DIRECT conversion ----
        bf16x8 thi[2];
        #pragma unroll
        for (int s = 0; s < 2; s++) {
            #pragma unroll
            for (int j = 0; j < 8; j++)
                thi[s][j] = (__bf16)vacc[8 * s + j];
        }

        // ---- aggregation: h2T = tT @ A32T (2 MFMA; + b2 folded into init) ----
        #pragma unroll
        for (int k = 0; k < 16; k++) vacc[k] = b2r[k];
        vacc = __builtin_amdgcn_mfma_f32_32x32x16_bf16(thi[0], a32hi[0], vacc, 0, 0, 0);
        vacc = __builtin_amdgcn_mfma_f32_32x32x16_bf16(thi[1], a32hi[1], vacc, 0, 0, 0);

        // ---- epilogue: lane=node, regs=hidden -> in-register reduction ----
        float ssum = 0.0f;
        #pragma unroll
        for (int k = 0; k < 16; k++)
            ssum = fmaf(fmaxf(vacc[k], 0.0f), woutr[k], ssum);
        ssum += __shfl_xor(ssum, 32, 64);          // other hidden half
        float o = fmaxf(ssum + boutv, 0.0f);       // relu per node
        o += __shfl_xor(o, 1, 64);
        o += __shfl_xor(o, 2, 64);
        o += __shfl_xor(o, 4, 64);                 // sum 8 nodes of my graph
        if (q == 0 && n8 == 0) {
            long long gg = gbase + g;
            if (gg < (long long)B) out[gg] = o * 0.125f;
        }
        buf ^= 1;
    }
}

extern "C" void kernel_launch(void* const* d_in, const int* in_sizes, int n_in,
                              void* d_out, int out_size, void* d_ws, size_t ws_size,
                              hipStream_t stream) {
    const float* x    = (const float*)d_in[0];
    const int*   ei   = (const int*)d_in[1];
    const float* W1   = (const float*)d_in[2];
    const float* b1   = (const float*)d_in[3];
    const float* W2   = (const float*)d_in[4];
    const float* b2   = (const float*)d_in[5];
    const float* Wout = (const float*)d_in[6];
    const float* bout = (const float*)d_in[7];
    float* out = (float*)d_out;
    (void)d_ws; (void)ws_size; (void)out_size; (void)n_in;

    const int B = in_sizes[0] / 24;                 // 262144
    const int ntiles = (B + GPT - 1) / GPT;         // 16384
    const int grid = ntiles < 2048 ? ntiles : 2048; // grid-stride, 8 iters/block
    gnn_kernel<<<grid, 256, 0, stream>>>(x, ei, W1, b1, W2, b2, Wout, bout, out, B, ntiles);
}

// Round 16
// 35.245 us; speedup vs baseline: 1.1832x; 1.0553x over previous
//
#include <hip/hip_runtime.h>

// VanillaGNN via MFMA: B=262144 graphs, N=8 nodes, DIN=3, DH=32, DOUT=1.
// Round-15 base (37.2us) + ONE change: drop plo (h1-side lo in GEMM1) —
// exact mirror of the r15-measured-free w2lo drop. GEMM1 = 2 MFMA,
// -32 VALU/tile, -16 transient regs (target: total <=128 -> 4 blocks/CU).
// Precision ledger (all measured-free at absmax 1.2207e-4 = bf16-grid floor):
//   tlo (r12/r13), w2lo + a32lo (r15). plo estimated <=2e-4 added.
// Pre-commit: absmax > 4.5e-4 -> restore plo, precision drops exhausted.
// Chain per wave (4 graphs = 32 node-rows):
//   y = A@x (24 fma) -> L1: P = W1split @ ysplit + b1 (2 kappa-packed MFMA,
//   relu) -> GEMM1: t = bf16(h1) @ bf16(W2) (2 MFMA; pi both sides) ->
//   AGG: h2T = bf16(tT) @ bf16(A32T) (2 MFMA) -> in-register Wout reduction.
// Verified layouts (gfx950 mfma_f32_32x32x16_bf16, rounds 3-15):
//   A: lane row=l&31, k=s*16+8*(l>>5)+j   B: col=l&31, same k
//   C/D: col=l&31, row=(reg&3)+8*(reg>>2)+4*(l>>5)
// pi(kk) = rr(kk) = (kk&3)+8*(kk>>2)+4q  (logical index of reg kk).
// FETCH_SIZE ~12.3MB is the spill canary. NEVER force the reg bin via
// launch_bounds (r9/r12 spill lesson).

typedef __bf16 bf16x8 __attribute__((ext_vector_type(8)));
typedef float  f32x16 __attribute__((ext_vector_type(16)));

#define GPT 16  // graphs per block tile (4 waves x 4 graphs)

__global__ __launch_bounds__(256, 2) void gnn_kernel(
    const float* __restrict__ x,       // [B,8,3]
    const int* __restrict__ ei,        // [2,32] int32
    const float* __restrict__ W1,      // [3,32]
    const float* __restrict__ b1,      // [32]
    const float* __restrict__ W2,      // [32,32]
    const float* __restrict__ b2,      // [32]
    const float* __restrict__ Wout,    // [32]
    const float* __restrict__ bout,    // [1]
    float* __restrict__ out,           // [B]
    int B, int ntiles)
{
    __shared__ float As[64];           // A[n][m] (n=dst)
    __shared__ float degs[8], dinvs[8];
    __shared__ float W1s[96], b1s[32], W2s[1024], b2s[32], Wouts[32];
    __shared__ float xs[2][GPT * 24];  // double-buffered [g][8][3]

    const int tid = threadIdx.x;

    // ---- stage weights / build A (once per block) ----
    if (tid < 96) W1s[tid] = W1[tid];
    if (tid < 64) As[tid] = 0.0f;
    if (tid < 32) { b1s[tid] = b1[tid]; b2s[tid] = b2[tid]; Wouts[tid] = Wout[tid]; }
    if (tid < 8)  degs[tid] = 1.0f;
    for (int i = tid; i < 1024; i += 256) W2s[i] = W2[i];
    __syncthreads();
    if (tid < 32) { int d = ei[32 + tid]; atomicAdd(&degs[d], 1.0f); }
    __syncthreads();
    if (tid < 8) dinvs[tid] = 1.0f / sqrtf(degs[tid]);
    __syncthreads();
    if (tid < 32) {
        int s = ei[tid], d = ei[32 + tid];
        atomicAdd(&As[d * 8 + s], dinvs[s] * dinvs[d]);
    } else if (tid < 40) {
        int n = tid - 32;
        atomicAdd(&As[n * 8 + n], dinvs[n] * dinvs[n]);
    }
    __syncthreads();

    // ---- per-lane constants ----
    const int lane = tid & 63;
    const int wv   = tid >> 6;    // wave 0..3
    const int r    = lane & 31;
    const int q    = lane >> 5;   // k-half / row-half selector
    const int n8   = r & 7;       // node within graph
    const int gl   = r >> 3;      // graph within wave
    const int g    = wv * 4 + gl; // block-local graph

    float arow[8];
    #pragma unroll
    for (int m = 0; m < 8; m++) arow[m] = As[n8 * 8 + m];

    // W1^T A-frags, kappa-packed: slots 0-2 = W1[j][r] (hi step0 / lo step1),
    // slot 3 = b1[r] (hi step0 / lo step1; paired with B slot3 = q?0:1)
    bf16x8 w1Ahi, w1Alo;
    #pragma unroll
    for (int j = 0; j < 8; j++) { w1Ahi[j] = (__bf16)0.0f; w1Alo[j] = (__bf16)0.0f; }
    #pragma unroll
    for (int j = 0; j < 3; j++) {
        float v = W1s[j * 32 + r];
        __bf16 h = (__bf16)v;
        w1Ahi[j] = h; w1Alo[j] = (__bf16)(v - (float)h);
    }
    {
        float v = b1s[r];
        __bf16 h = (__bf16)v;
        w1Ahi[3] = h; w1Alo[3] = (__bf16)(v - (float)h);
    }

    // W2 B-frags in pi-order (hi only): slot (s,j), kk=8s+j ->
    //   hidden-in rr(kk) = (kk&3)+8*(kk>>2)+4q ; value bf16(W2[rr(kk)][r])
    bf16x8 w2hi[2];
    #pragma unroll
    for (int s = 0; s < 2; s++) {
        #pragma unroll
        for (int j = 0; j < 8; j++) {
            int kk = 8 * s + j;
            int hid = (kk & 3) + 8 * (kk >> 2) + 4 * q;
            w2hi[s][j] = (__bf16)W2s[hid * 32 + r];
        }
    }
    // A32T B-frags in pi-order (hi only): slot (s,j), kk=8s+j
    //   -> node (kk&3)+4q of graph kk>>2, gated to own graph
    bf16x8 a32hi[2];
    #pragma unroll
    for (int s = 0; s < 2; s++) {
        #pragma unroll
        for (int j = 0; j < 8; j++) {
            int kk = 8 * s + j;
            float v = ((kk >> 2) == gl) ? arow[(kk & 3) + 4 * q] : 0.0f;
            a32hi[s][j] = (__bf16)v;
        }
    }
    // epilogue per-reg constants: reg k holds hidden row hk = rr(k)
    float b2r[16], woutr[16];
    #pragma unroll
    for (int k = 0; k < 16; k++) {
        int hk = (k & 3) + 8 * (k >> 2) + 4 * q;
        b2r[k] = b2s[hk]; woutr[k] = Wouts[hk];
    }
    const float boutv = bout[0];

    // ---- x prefetch (tile 0) ----
    const float4* x4 = reinterpret_cast<const float4*>(x);
    float4 nxt;
    if (tid < 96 && blockIdx.x < ntiles)
        nxt = x4[(long long)blockIdx.x * 96 + tid];
    int buf = 0;

    // ---- tile loop: 1 barrier/tile; prefetch issued after the barrier ----
    for (int tile = blockIdx.x; tile < ntiles; tile += gridDim.x) {
        const long long gbase = (long long)tile * GPT;
        if (tid < 96) *reinterpret_cast<float4*>(&xs[buf][tid * 4]) = nxt;
        __syncthreads();
        int tnext = tile + gridDim.x;
        if (tid < 96 && tnext < ntiles)
            nxt = x4[(long long)tnext * 96 + tid];   // in flight during compute

        // ---- y = A@x for node-row r (24 fma) ----
        float xv[24];
        #pragma unroll
        for (int i = 0; i < 6; i++) {
            float4 v = *reinterpret_cast<float4*>(&xs[buf][g * 24 + i * 4]);
            xv[4 * i] = v.x; xv[4 * i + 1] = v.y; xv[4 * i + 2] = v.z; xv[4 * i + 3] = v.w;
        }
        float y0 = 0.f, y1 = 0.f, y2 = 0.f;
        #pragma unroll
        for (int m = 0; m < 8; m++) {
            y0 = fmaf(arow[m], xv[m * 3 + 0], y0);
            y1 = fmaf(arow[m], xv[m * 3 + 1], y1);
            y2 = fmaf(arow[m], xv[m * 3 + 2], y2);
        }

        // ---- shared accumulator for all three MFMA stages ----
        f32x16 vacc;

        // ---- layer 1 via 2 kappa-packed MFMAs (bias in slot 3) ----
        bf16x8 yB;
        #pragma unroll
        for (int j = 0; j < 8; j++) yB[j] = (__bf16)0.0f;
        {
            __bf16 h0 = (__bf16)y0, h1b = (__bf16)y1, h2b = (__bf16)y2;
            __bf16 l0 = (__bf16)(y0 - (float)h0);
            __bf16 l1 = (__bf16)(y1 - (float)h1b);
            __bf16 l2 = (__bf16)(y2 - (float)h2b);
            yB[0] = q ? l0 : h0; yB[1] = q ? l1 : h1b; yB[2] = q ? l2 : h2b;
            yB[3] = q ? (__bf16)0.0f : (__bf16)1.0f;
        }
        #pragma unroll
        for (int k = 0; k < 16; k++) vacc[k] = 0.0f;
        vacc = __builtin_amdgcn_mfma_f32_32x32x16_bf16(w1Ahi, yB, vacc, 0, 0, 0);
        vacc = __builtin_amdgcn_mfma_f32_32x32x16_bf16(w1Alo, yB, vacc, 0, 0, 0);

        // ---- relu -> h1 (lane=node, regs=hidden rr), hi-only A-frags ----
        bf16x8 phi[2];
        #pragma unroll
        for (int s = 0; s < 2; s++) {
            #pragma unroll
            for (int j = 0; j < 8; j++)
                phi[s][j] = (__bf16)fmaxf(vacc[8 * s + j], 0.0f);
        }

        // ---- GEMM1: t = bf16(h1) @ bf16(W2) (2 MFMA; pi both sides) ----
        #pragma unroll
        for (int k = 0; k < 16; k++) vacc[k] = 0.0f;
        vacc = __builtin_amdgcn_mfma_f32_32x32x16_bf16(phi[0], w2hi[0], vacc, 0, 0, 0);
        vacc = __builtin_amdgcn_mfma_f32_32x32x16_bf16(phi[1], w2hi[1], vacc, 0, 0, 0);

        // ---- tT A-frag: hi-only DIRECT conversion ----
        bf16x8 thi[2];
        #pragma unroll
        for (int s = 0; s < 2; s++) {
            #pragma unroll
            for (int j = 0; j < 8; j++)
                thi[s][j] = (__bf16)vacc[8 * s + j];
        }

        // ---- aggregation: h2T = tT @ A32T (2 MFMA; + b2 folded into init) ----
        #pragma unroll
        for (int k = 0; k < 16; k++) vacc[k] = b2r[k];
        vacc = __builtin_amdgcn_mfma_f32_32x32x16_bf16(thi[0], a32hi[0], vacc, 0, 0, 0);
        vacc = __builtin_amdgcn_mfma_f32_32x32x16_bf16(thi[1], a32hi[1], vacc, 0, 0, 0);

        // ---- epilogue: lane=node, regs=hidden -> in-register reduction ----
        float ssum = 0.0f;
        #pragma unroll
        for (int k = 0; k < 16; k++)
            ssum = fmaf(fmaxf(vacc[k], 0.0f), woutr[k], ssum);
        ssum += __shfl_xor(ssum, 32, 64);          // other hidden half
        float o = fmaxf(ssum + boutv, 0.0f);       // relu per node
        o += __shfl_xor(o, 1, 64);
        o += __shfl_xor(o, 2, 64);
        o += __shfl_xor(o, 4, 64);                 // sum 8 nodes of my graph
        if (q == 0 && n8 == 0) {
            long long gg = gbase + g;
            if (gg < (long long)B) out[gg] = o * 0.125f;
        }
        buf ^= 1;
    }
}

extern "C" void kernel_launch(void* const* d_in, const int* in_sizes, int n_in,
                              void* d_out, int out_size, void* d_ws, size_t ws_size,
                              hipStream_t stream) {
    const float* x    = (const float*)d_in[0];
    const int*   ei   = (const int*)d_in[1];
    const float* W1   = (const float*)d_in[2];
    const float* b1   = (const float*)d_in[3];
    const float* W2   = (const float*)d_in[4];
    const float* b2   = (const float*)d_in[5];
    const float* Wout = (const float*)d_in[6];
    const float* bout = (const float*)d_in[7];
    float* out = (float*)d_out;
    (void)d_ws; (void)ws_size; (void)out_size; (void)n_in;

    const int B = in_sizes[0] / 24;                 // 262144
    const int ntiles = (B + GPT - 1) / GPT;         // 16384
    const int grid = ntiles < 2048 ? ntiles : 2048; // grid-stride, 8 iters/block
    gnn_kernel<<<grid, 256, 0, stream>>>(x, ei, W1, b1, W2, b2, Wout, bout, out, B, ntiles);
}